// Round 1
// baseline (389.415 us; speedup 1.0000x reference)
//
#include <hip/hip_runtime.h>
#include <math.h>

// Problem constants
#define B2     2
#define CIN    31
#define HIN    128
#define CC     64      // conv out channels / GAT dim
#define NN     4096    // 64*64 nodes
#define NCH    16      // kNN j-chunks

// ---------------- workspace layout (in 4-byte elements) ----------------
constexpr int OF_YN   = 0;                         // [B,N,64] fp32
constexpr int OF_SQ   = OF_YN   + B2*NN*CC;        // [B,N]
constexpr int OF_HCAT = OF_SQ   + B2*NN;           // [B,N,128] heads pre-agg
constexpr int OF_FV   = OF_HCAT + B2*NN*128;       // 4 x [B*N]: f1_0,f2_0,f1_1,f2_1
constexpr int OF_HAGG = OF_FV   + 4*B2*NN;         // [B,N,128] post-agg concat
constexpr int OF_HO   = OF_HAGG + B2*NN*128;       // [B,N,64] layer2 pre-agg
constexpr int OF_FO   = OF_HO   + B2*NN*CC;        // 2 x [B*N]
constexpr int OF_Z    = OF_FO   + 2*B2*NN;         // [B,N,64] elu+log_softmax out
constexpr int OF_PD   = OF_Z    + B2*NN*CC;        // partial top7 dists [B*N][NCH][7]
constexpr int OF_PI   = OF_PD   + B2*NN*NCH*7;     // partial top7 idx (int)
constexpr int OF_NBR  = OF_PI   + B2*NN*NCH*7;     // [B*N][7] final neighbor idx (int)
constexpr int OF_WT   = OF_NBR  + B2*NN*7;         // convT weights [9][64][64]
constexpr int OF_WHT  = OF_WT   + 9*64*64;         // head conv weights [279][64]
// end = OF_WHT + 279*64  (~22.7 MB total)

// ---------------- K0: weight transposes ----------------
__global__ __launch_bounds__(256) void k_prep(const float* __restrict__ wlast,
                                              const float* __restrict__ whead,
                                              float* __restrict__ wT,
                                              float* __restrict__ whT) {
  int idx = blockIdx.x*256 + threadIdx.x;
  if (idx < 36864) {
    // wT[kk][ci][co] = wlast[ci][co][kk]   (wlast: [in=64][out=64][3][3])
    int co = idx & 63, ci = (idx >> 6) & 63, kk = idx >> 12;
    wT[idx] = wlast[(ci*64 + co)*9 + kk];
  } else if (idx < 36864 + 279*64) {
    int j = idx - 36864;
    int c = j & 63, q = j >> 6;              // whT[q][c] = whead[c][q], q<279
    whT[j] = whead[c*279 + q];
  }
}

// ---------------- K1: head conv (31->64, k3 s2 p1) + sq norms ----------------
__global__ __launch_bounds__(256) void k_head(const float* __restrict__ x,
                                              const float* __restrict__ whT,
                                              const float* __restrict__ bias,
                                              float* __restrict__ yn,
                                              float* __restrict__ sq) {
  int lane = threadIdx.x & 63, wv = threadIdx.x >> 6;
  int gbase = blockIdx.x*32 + wv*8;            // 8 nodes per wave
  __shared__ float patch[4][8][280];
  for (int nn = 0; nn < 8; ++nn) {
    int g = gbase + nn;
    int b = g >> 12, n = g & 4095;
    int oh = n >> 6, ow = n & 63;
    for (int q = lane; q < 279; q += 64) {
      int ci = q / 9, r = q - ci*9;
      int ky = r / 3, kx = r - ky*3;
      int ih = 2*oh - 1 + ky, iw = 2*ow - 1 + kx;
      float v = 0.f;
      if (ih >= 0 && ih < 128 && iw >= 0 && iw < 128)
        v = x[((b*CIN + ci)*128 + ih)*128 + iw];
      patch[wv][nn][q] = v;
    }
  }
  __syncthreads();
  int c = lane;
  float acc[8];
  float bv = bias[c];
  #pragma unroll
  for (int nn = 0; nn < 8; ++nn) acc[nn] = bv;
  for (int q = 0; q < 279; ++q) {
    float wgt = whT[q*64 + c];
    #pragma unroll
    for (int nn = 0; nn < 8; ++nn) acc[nn] += patch[wv][nn][q] * wgt;
  }
  for (int nn = 0; nn < 8; ++nn) {
    int g = gbase + nn;
    yn[g*64 + c] = acc[nn];
    float s = acc[nn]*acc[nn];
    #pragma unroll
    for (int off = 32; off > 0; off >>= 1) s += __shfl_xor(s, off);
    if (lane == 0) sq[g] = s;
  }
}

// ---------------- K2: fused pairwise dist + stable top-7 (per j-chunk) -------
__global__ __launch_bounds__(256) void k_knn(const float* __restrict__ yn,
                                             const float* __restrict__ sq,
                                             float* __restrict__ pd,
                                             int* __restrict__ pidx) {
  __shared__ float Yj[128*64];
  __shared__ float sqj[256];
  int b = blockIdx.z;
  int i0 = blockIdx.x * 256;
  int j0 = blockIdx.y * 256;
  int tid = threadIdx.x;
  sqj[tid] = sq[b*NN + j0 + tid];
  int i = i0 + tid;
  float4 yi[16];
  {
    const float4* yr = (const float4*)(yn + (b*NN + i)*64);
    #pragma unroll
    for (int r = 0; r < 16; ++r) yi[r] = yr[r];
  }
  float sqi = sq[b*NN + i];
  float d7[7]; int x7[7];
  #pragma unroll
  for (int k = 0; k < 7; ++k) { d7[k] = 3.0e38f; x7[k] = 0x7fffffff; }
  for (int sub = 0; sub < 2; ++sub) {
    int jb = j0 + sub*128;
    __syncthreads();
    {
      const float4* src = (const float4*)(yn + (b*NN + jb)*64);
      for (int k2 = tid; k2 < 2048; k2 += 256) ((float4*)Yj)[k2] = src[k2];
    }
    __syncthreads();
    for (int j = 0; j < 128; ++j) {
      const float4* Yr = (const float4*)(Yj + j*64);
      float a0 = 0, a1 = 0, a2 = 0, a3 = 0;
      #pragma unroll
      for (int r = 0; r < 16; ++r) {
        float4 v = Yr[r];
        a0 += yi[r].x*v.x; a1 += yi[r].y*v.y;
        a2 += yi[r].z*v.z; a3 += yi[r].w*v.w;
      }
      float d2 = sqi + sqj[sub*128 + j] - 2.f*((a0+a1)+(a2+a3));
      if (d2 < d7[6]) {            // strict <  => stable (earlier j wins ties)
        int jj = jb + j;
        int k = 6;
        #pragma unroll
        for (int t = 5; t >= 0; --t) {
          if (d2 < d7[t]) { d7[t+1] = d7[t]; x7[t+1] = x7[t]; k = t; }
        }
        d7[k] = d2; x7[k] = jj;
      }
    }
  }
  int base = ((b*NN + i)*NCH + blockIdx.y)*7;
  #pragma unroll
  for (int k = 0; k < 7; ++k) { pd[base+k] = d7[k]; pidx[base+k] = x7[k]; }
}

// ---------------- K3: merge per-chunk top7 -> final 7 neighbors --------------
__global__ __launch_bounds__(256) void k_merge(const float* __restrict__ pd,
                                               const int* __restrict__ pidx,
                                               int* __restrict__ nbr) {
  int g = blockIdx.x*256 + threadIdx.x;    // 0..8191
  float d7[7]; int x7[7];
  #pragma unroll
  for (int k = 0; k < 7; ++k) { d7[k] = 3.0e38f; x7[k] = 0x7fffffff; }
  int base = g*NCH*7;
  for (int e = 0; e < NCH*7; ++e) {        // chunks ascending => j ascending
    float d = pd[base+e]; int jj = pidx[base+e];
    if (d < d7[6]) {
      int k = 6;
      #pragma unroll
      for (int t = 5; t >= 0; --t) {
        if (d < d7[t]) { d7[t+1] = d7[t]; x7[t+1] = x7[t]; k = t; }
      }
      d7[k] = d; x7[k] = jj;
    }
  }
  #pragma unroll
  for (int k = 0; k < 7; ++k) nbr[g*7 + k] = x7[k];
}

// ---------------- K4: hcat = yn @ [W0|W1]  ([B,N,64] -> [B,N,128]) ----------
__global__ __launch_bounds__(256) void k_hcat(const float* __restrict__ yn,
                                              const float* __restrict__ W0,
                                              const float* __restrict__ W1,
                                              float* __restrict__ hcat) {
  __shared__ float Ws[64*128];
  __shared__ float yt[16*64];
  int b = blockIdx.x >> 8, n0 = (blockIdx.x & 255)*16;
  int tid = threadIdx.x;
  for (int idx = tid; idx < 8192; idx += 256) {
    int k = idx >> 7, c = idx & 127;
    Ws[idx] = (c < 64) ? W0[k*64 + c] : W1[k*64 + (c - 64)];
  }
  {
    const float4* src = (const float4*)(yn + (b*NN + n0)*64);
    for (int idx = tid; idx < 256; idx += 256) ((float4*)yt)[idx] = src[idx];
  }
  __syncthreads();
  int c = tid & 127, nh = tid >> 7;
  for (int nn = 0; nn < 8; ++nn) {
    int node = nh*8 + nn;
    const float* yr = yt + node*64;
    float acc = 0.f;
    #pragma unroll
    for (int k = 0; k < 64; ++k) acc += yr[k] * Ws[k*128 + c];
    hcat[(b*NN + n0 + node)*128 + c] = acc;
  }
}

// ---------------- K5: f-vectors layer1 (4 dots of len 64 per node) ----------
__global__ __launch_bounds__(256) void k_fv1(const float* __restrict__ hcat,
                                             const float* __restrict__ a0,
                                             const float* __restrict__ a1,
                                             float* __restrict__ fv) {
  int lane = threadIdx.x & 63, wv = threadIdx.x >> 6;
  int g = blockIdx.x*4 + wv;
  const float* hr = hcat + g*128;
  float h0 = hr[lane], h1 = hr[64 + lane];
  float s00 = h0*a0[lane], s01 = h0*a0[64+lane];
  float s10 = h1*a1[lane], s11 = h1*a1[64+lane];
  #pragma unroll
  for (int off = 32; off > 0; off >>= 1) {
    s00 += __shfl_xor(s00, off); s01 += __shfl_xor(s01, off);
    s10 += __shfl_xor(s10, off); s11 += __shfl_xor(s11, off);
  }
  if (lane == 0) {
    fv[g] = s00; fv[8192 + g] = s01; fv[16384 + g] = s10; fv[24576 + g] = s11;
  }
}

// ---------------- K6: GAT layer1 aggregation (2 heads) + relu ---------------
__global__ __launch_bounds__(128) void k_agg1(const float* __restrict__ hcat,
                                              const float* __restrict__ fv,
                                              const int* __restrict__ nbr,
                                              float* __restrict__ hagg) {
  int g = blockIdx.x, c = threadIdx.x;
  int b = g >> 12;
  int head = c >> 6;
  int jj[7];
  #pragma unroll
  for (int t = 0; t < 7; ++t) jj[t] = nbr[g*7 + t];
  float f1 = fv[head*16384 + g];
  const float* f2p = fv + head*16384 + 8192 + (b << 12);
  float e[7], m = -3.0e38f;
  #pragma unroll
  for (int t = 0; t < 7; ++t) {
    float v = f1 + f2p[jj[t]];
    v = (v >= 0.f) ? v : 0.2f*v;
    e[t] = v; m = fmaxf(m, v);
  }
  float w[7], s = 0.f;
  #pragma unroll
  for (int t = 0; t < 7; ++t) { w[t] = expf(e[t] - m); s += w[t]; }
  float acc = 0.f;
  #pragma unroll
  for (int t = 0; t < 7; ++t)
    acc += (w[t]/s) * hcat[((b << 12) + jj[t])*128 + c];
  hagg[g*128 + c] = fmaxf(acc, 0.f);
}

// ---------------- K7: ho = hagg @ W_out  ([B,N,128] -> [B,N,64]) ------------
__global__ __launch_bounds__(256) void k_ho(const float* __restrict__ hagg,
                                            const float* __restrict__ Wout,
                                            float* __restrict__ ho) {
  __shared__ float Ws[128*64];
  __shared__ float ht[16*128];
  int b = blockIdx.x >> 8, n0 = (blockIdx.x & 255)*16;
  int tid = threadIdx.x;
  for (int idx = tid; idx < 8192; idx += 256) Ws[idx] = Wout[idx];
  {
    const float4* src = (const float4*)(hagg + (b*NN + n0)*128);
    for (int idx = tid; idx < 512; idx += 256) ((float4*)ht)[idx] = src[idx];
  }
  __syncthreads();
  int c = tid & 63, ngrp = tid >> 6;
  for (int nn = 0; nn < 4; ++nn) {
    int node = ngrp*4 + nn;
    const float* hr = ht + node*128;
    float acc = 0.f;
    #pragma unroll
    for (int k = 0; k < 128; ++k) acc += hr[k] * Ws[k*64 + c];
    ho[(b*NN + n0 + node)*64 + c] = acc;
  }
}

// ---------------- K8: f-vectors layer2 --------------------------------------
__global__ __launch_bounds__(256) void k_fv2(const float* __restrict__ ho,
                                             const float* __restrict__ aout,
                                             float* __restrict__ fo) {
  int lane = threadIdx.x & 63, wv = threadIdx.x >> 6;
  int g = blockIdx.x*4 + wv;
  float v = ho[g*64 + lane];
  float s0 = v*aout[lane], s1 = v*aout[64+lane];
  #pragma unroll
  for (int off = 32; off > 0; off >>= 1) {
    s0 += __shfl_xor(s0, off); s1 += __shfl_xor(s1, off);
  }
  if (lane == 0) { fo[g] = s0; fo[8192 + g] = s1; }
}

// ---------------- K9: layer2 agg + elu + log_softmax ------------------------
__global__ __launch_bounds__(64) void k_agg2(const float* __restrict__ ho,
                                             const float* __restrict__ fo,
                                             const int* __restrict__ nbr,
                                             float* __restrict__ zbuf) {
  int g = blockIdx.x, c = threadIdx.x;
  int b = g >> 12;
  int jj[7];
  #pragma unroll
  for (int t = 0; t < 7; ++t) jj[t] = nbr[g*7 + t];
  float f1 = fo[g];
  const float* f2p = fo + 8192 + (b << 12);
  float e[7], m = -3.0e38f;
  #pragma unroll
  for (int t = 0; t < 7; ++t) {
    float v = f1 + f2p[jj[t]];
    v = (v >= 0.f) ? v : 0.2f*v;
    e[t] = v; m = fmaxf(m, v);
  }
  float w[7], s = 0.f;
  #pragma unroll
  for (int t = 0; t < 7; ++t) { w[t] = expf(e[t] - m); s += w[t]; }
  float acc = 0.f;
  #pragma unroll
  for (int t = 0; t < 7; ++t)
    acc += (w[t]/s) * ho[((b << 12) + jj[t])*64 + c];
  float v = (acc > 0.f) ? acc : expm1f(acc);        // elu
  float mm = v;
  #pragma unroll
  for (int off = 32; off > 0; off >>= 1) mm = fmaxf(mm, __shfl_xor(mm, off));
  float ex = expf(v - mm), ss = ex;
  #pragma unroll
  for (int off = 32; off > 0; off >>= 1) ss += __shfl_xor(ss, off);
  zbuf[g*64 + c] = v - mm - logf(ss);
}

// ---------------- K10: ConvTranspose2d (64->64, k3 s2 p1 op1) ---------------
__global__ __launch_bounds__(256) void k_convt(const float* __restrict__ z,
                                               const float* __restrict__ wT,
                                               const float* __restrict__ bias,
                                               float* __restrict__ out) {
  int b = blockIdx.z, oy = blockIdx.y, ox0 = blockIdx.x * 16;
  int co = threadIdx.x & 63, p = threadIdx.x >> 6;
  int iy[2], kyv[2], nty;
  if (!(oy & 1)) { iy[0] = oy >> 1; kyv[0] = 1; nty = 1; }
  else {
    iy[0] = (oy - 1) >> 1; kyv[0] = 2; nty = 1;
    int i0 = (oy + 1) >> 1;
    if (i0 < 64) { iy[1] = i0; kyv[1] = 0; nty = 2; }
  }
  float bv = bias[co];
  float accs[4];
  for (int gg = 0; gg < 4; ++gg) {
    int ox = ox0 + gg*4 + p;
    int ix[2], kxv[2], ntx;
    if (!(ox & 1)) { ix[0] = ox >> 1; kxv[0] = 1; ntx = 1; }
    else {
      ix[0] = (ox - 1) >> 1; kxv[0] = 2; ntx = 1;
      int i0 = (ox + 1) >> 1;
      if (i0 < 64) { ix[1] = i0; kxv[1] = 0; ntx = 2; }
    }
    float acc = bv;
    for (int ty = 0; ty < nty; ++ty)
      for (int tx = 0; tx < ntx; ++tx) {
        const float* zr = z + ((b << 12) + iy[ty]*64 + ix[tx])*64;
        const float* wr = wT + (kyv[ty]*3 + kxv[tx])*4096 + co;
        float a = 0.f;
        #pragma unroll 8
        for (int ci = 0; ci < 64; ++ci) a += zr[ci] * wr[ci << 6];
        acc += a;
      }
    accs[gg] = acc;
  }
  __shared__ float st[1024];       // [co][16 ox-offsets]
  for (int gg = 0; gg < 4; ++gg) st[co*16 + gg*4 + p] = accs[gg];
  __syncthreads();
  for (int idx = threadIdx.x; idx < 1024; idx += 256) {
    int cc = idx >> 4, oxo = idx & 15;
    out[((b*64 + cc)*128 + oy)*128 + ox0 + oxo] = st[idx];
  }
}

// ---------------- launch ----------------------------------------------------
extern "C" void kernel_launch(void* const* d_in, const int* in_sizes, int n_in,
                              void* d_out, int out_size, void* d_ws, size_t ws_size,
                              hipStream_t stream) {
  const float* x      = (const float*)d_in[0];
  const float* w_head = (const float*)d_in[1];
  const float* b_head = (const float*)d_in[2];
  const float* W0     = (const float*)d_in[3];
  const float* a0     = (const float*)d_in[4];
  const float* W1     = (const float*)d_in[5];
  const float* a1     = (const float*)d_in[6];
  const float* W_out  = (const float*)d_in[7];
  const float* a_out  = (const float*)d_in[8];
  const float* w_last = (const float*)d_in[9];
  const float* b_last = (const float*)d_in[10];
  float* out = (float*)d_out;

  float* wsf = (float*)d_ws;
  int*   wsi = (int*)d_ws;
  float* yn   = wsf + OF_YN;
  float* sq   = wsf + OF_SQ;
  float* hcat = wsf + OF_HCAT;
  float* fv   = wsf + OF_FV;
  float* hagg = wsf + OF_HAGG;
  float* ho   = wsf + OF_HO;
  float* fo   = wsf + OF_FO;
  float* zbuf = wsf + OF_Z;
  float* pd   = wsf + OF_PD;
  int*   pidx = wsi + OF_PI;
  int*   nbr  = wsi + OF_NBR;
  float* wT   = wsf + OF_WT;
  float* whT  = wsf + OF_WHT;

  hipLaunchKernelGGL(k_prep,  dim3(214), dim3(256), 0, stream, w_last, w_head, wT, whT);
  hipLaunchKernelGGL(k_head,  dim3(256), dim3(256), 0, stream, x, whT, b_head, yn, sq);
  hipLaunchKernelGGL(k_knn,   dim3(16, NCH, 2), dim3(256), 0, stream, yn, sq, pd, pidx);
  hipLaunchKernelGGL(k_merge, dim3(32), dim3(256), 0, stream, pd, pidx, nbr);
  hipLaunchKernelGGL(k_hcat,  dim3(512), dim3(256), 0, stream, yn, W0, W1, hcat);
  hipLaunchKernelGGL(k_fv1,   dim3(2048), dim3(256), 0, stream, hcat, a0, a1, fv);
  hipLaunchKernelGGL(k_agg1,  dim3(8192), dim3(128), 0, stream, hcat, fv, nbr, hagg);
  hipLaunchKernelGGL(k_ho,    dim3(512), dim3(256), 0, stream, hagg, W_out, ho);
  hipLaunchKernelGGL(k_fv2,   dim3(2048), dim3(256), 0, stream, ho, a_out, fo);
  hipLaunchKernelGGL(k_agg2,  dim3(8192), dim3(64), 0, stream, ho, fo, nbr, zbuf);
  hipLaunchKernelGGL(k_convt, dim3(8, 128, 2), dim3(256), 0, stream, zbuf, wT, b_last, out);
}

// Round 2
// 333.553 us; speedup vs baseline: 1.1675x; 1.1675x over previous
//
#include <hip/hip_runtime.h>
#include <math.h>

// Problem constants
#define B2     2
#define CIN    31
#define CC     64      // conv out channels / GAT dim
#define NN     4096    // 64*64 nodes
#define NCH    8       // kNN j-splits (512 j each)

typedef short bf16x8 __attribute__((ext_vector_type(8)));
typedef float f32x4  __attribute__((ext_vector_type(4)));

__device__ inline unsigned short f2bf(float f) {
  union { float f; unsigned u; } v; v.f = f;
  unsigned r = (v.u + 0x7fffu + ((v.u >> 16) & 1u)) >> 16;
  return (unsigned short)r;
}
__device__ inline float bf2f(unsigned short h) {
  union { float f; unsigned u; } v; v.u = ((unsigned)h) << 16;
  return v.f;
}

// ---------------- workspace layout (in 4-byte elements) ----------------
constexpr int OF_YN   = 0;                         // [B,N,64] fp32
constexpr int OF_SQ   = OF_YN   + B2*NN*CC;        // [B,N]
constexpr int OF_HCAT = OF_SQ   + B2*NN;           // [B,N,128]
constexpr int OF_FV   = OF_HCAT + B2*NN*128;       // 4 x [B*N]
constexpr int OF_HAGG = OF_FV   + 4*B2*NN;         // [B,N,128]
constexpr int OF_HO   = OF_HAGG + B2*NN*128;       // [B,N,64]
constexpr int OF_FO   = OF_HO   + B2*NN*CC;        // 2 x [B*N]
constexpr int OF_Z    = OF_FO   + 2*B2*NN;         // [B,N,64]
constexpr int OF_PD   = OF_Z    + B2*NN*CC;        // partial top7 dists [B*N][NCH][7]
constexpr int OF_PI   = OF_PD   + B2*NN*NCH*7;     // partial top7 idx (int)
constexpr int OF_NBR  = OF_PI   + B2*NN*NCH*7;     // [B*N][7] neighbor idx (int)
constexpr int OF_WT   = OF_NBR  + B2*NN*7;         // convT weights [9][64][64]
constexpr int OF_WHT  = OF_WT   + 9*64*64;         // head conv weights [279][64]
constexpr int OF_YNH  = OF_WHT  + 279*64;          // bf16 hi [B,N,64] (ushort)
constexpr int OF_YNL  = OF_YNH  + B2*NN*CC/2;      // bf16 lo [B,N,64] (ushort)
// end ~= 21.1 MB

// ---------------- K0: weight transposes ----------------
__global__ __launch_bounds__(256) void k_prep(const float* __restrict__ wlast,
                                              const float* __restrict__ whead,
                                              float* __restrict__ wT,
                                              float* __restrict__ whT) {
  int idx = blockIdx.x*256 + threadIdx.x;
  if (idx < 36864) {
    int co = idx & 63, ci = (idx >> 6) & 63, kk = idx >> 12;
    wT[idx] = wlast[(ci*64 + co)*9 + kk];
  } else if (idx < 36864 + 279*64) {
    int j = idx - 36864;
    int c = j & 63, q = j >> 6;
    whT[j] = whead[c*279 + q];
  }
}

// ---------------- K1: head conv (31->64, k3 s2 p1) + sq + bf16 split --------
__global__ __launch_bounds__(256) void k_head(const float* __restrict__ x,
                                              const float* __restrict__ whT,
                                              const float* __restrict__ bias,
                                              float* __restrict__ yn,
                                              float* __restrict__ sq,
                                              unsigned short* __restrict__ ynh,
                                              unsigned short* __restrict__ ynl) {
  int lane = threadIdx.x & 63, wv = threadIdx.x >> 6;
  int gbase = blockIdx.x*32 + wv*8;
  __shared__ float patch[4][8][280];
  for (int nn = 0; nn < 8; ++nn) {
    int g = gbase + nn;
    int b = g >> 12, n = g & 4095;
    int oh = n >> 6, ow = n & 63;
    for (int q = lane; q < 279; q += 64) {
      int ci = q / 9, r = q - ci*9;
      int ky = r / 3, kx = r - ky*3;
      int ih = 2*oh - 1 + ky, iw = 2*ow - 1 + kx;
      float v = 0.f;
      if (ih >= 0 && ih < 128 && iw >= 0 && iw < 128)
        v = x[((b*CIN + ci)*128 + ih)*128 + iw];
      patch[wv][nn][q] = v;
    }
  }
  __syncthreads();
  int c = lane;
  float acc[8];
  float bv = bias[c];
  #pragma unroll
  for (int nn = 0; nn < 8; ++nn) acc[nn] = bv;
  for (int q = 0; q < 279; ++q) {
    float wgt = whT[q*64 + c];
    #pragma unroll
    for (int nn = 0; nn < 8; ++nn) acc[nn] += patch[wv][nn][q] * wgt;
  }
  for (int nn = 0; nn < 8; ++nn) {
    int g = gbase + nn;
    float y = acc[nn];
    yn[g*64 + c] = y;
    unsigned short hb = f2bf(y);
    ynh[g*64 + c] = hb;
    ynl[g*64 + c] = f2bf(y - bf2f(hb));
    float s = y*y;
    #pragma unroll
    for (int off = 32; off > 0; off >>= 1) s += __shfl_xor(s, off);
    if (lane == 0) sq[g] = s;
  }
}

// ---------------- K2: MFMA split-bf16 Gram + fused top-7 --------------------
// grid (32 i-blocks of 128 rows, 8 j-splits of 512, 2 batches), 256 threads.
__global__ __launch_bounds__(256, 2) void k_knn2(const unsigned short* __restrict__ ynh,
                                                 const unsigned short* __restrict__ ynl,
                                                 const float* __restrict__ sq,
                                                 float* __restrict__ pd,
                                                 int* __restrict__ pidx) {
  __shared__ unsigned short Bh[64*72];
  __shared__ unsigned short Bl[64*72];
  __shared__ float S[128*65];
  __shared__ float sqj[64];

  int b = blockIdx.z, ib = blockIdx.x, jsp = blockIdx.y;
  int i0 = ib*128;
  int jbase = jsp*512;
  int tid = threadIdx.x;
  int lane = tid & 63, w = tid >> 6;
  int quad = lane >> 4, m = lane & 15;

  const unsigned short* ynh_b = ynh + (size_t)b*NN*64;
  const unsigned short* ynl_b = ynl + (size_t)b*NN*64;

  // A fragments in registers: wave w covers i-subtiles {2w, 2w+1}
  bf16x8 ah[2][2], al[2][2];
  float sqi_v[2][4];
  #pragma unroll
  for (int is = 0; is < 2; ++is) {
    int row = i0 + (2*w + is)*16 + m;
    ah[is][0] = *(const bf16x8*)(ynh_b + row*64 + quad*8);
    ah[is][1] = *(const bf16x8*)(ynh_b + row*64 + 32 + quad*8);
    al[is][0] = *(const bf16x8*)(ynl_b + row*64 + quad*8);
    al[is][1] = *(const bf16x8*)(ynl_b + row*64 + 32 + quad*8);
    #pragma unroll
    for (int r = 0; r < 4; ++r)
      sqi_v[is][r] = sq[b*NN + i0 + (2*w + is)*16 + quad*4 + r];
  }

  // top-7 scan state: thread scans row (tid>>1), j-half (tid&1)
  float d7[7]; int x7[7];
  #pragma unroll
  for (int k = 0; k < 7; ++k) { d7[k] = 3.0e38f; x7[k] = 0x7fffffff; }
  int srow = tid >> 1, shalf = tid & 1;

  auto stageB = [&](int c) {
    int jt = jbase + c*64;
    #pragma unroll
    for (int r2 = 0; r2 < 2; ++r2) {
      int row = (tid >> 3) + 32*r2, oct = tid & 7;
      *(uint4*)&Bh[row*72 + oct*8] = *(const uint4*)(ynh_b + (jt + row)*64 + oct*8);
      *(uint4*)&Bl[row*72 + oct*8] = *(const uint4*)(ynl_b + (jt + row)*64 + oct*8);
    }
    if (tid < 64) sqj[tid] = sq[b*NN + jt + tid];
  };

  stageB(0);

  for (int c = 0; c < 8; ++c) {
    __syncthreads();                       // B(c)/sqj(c) ready; S(c-1) scans done
    f32x4 acc[2][4];
    #pragma unroll
    for (int is = 0; is < 2; ++is)
      #pragma unroll
      for (int jn = 0; jn < 4; ++jn)
        acc[is][jn] = (f32x4){0.f, 0.f, 0.f, 0.f};

    #pragma unroll
    for (int kh = 0; kh < 2; ++kh) {
      bf16x8 bh[4], bl[4];
      #pragma unroll
      for (int jn = 0; jn < 4; ++jn) {
        bh[jn] = *(const bf16x8*)&Bh[(jn*16 + m)*72 + kh*32 + quad*8];
        bl[jn] = *(const bf16x8*)&Bl[(jn*16 + m)*72 + kh*32 + quad*8];
      }
      #pragma unroll
      for (int jn = 0; jn < 4; ++jn)
        #pragma unroll
        for (int is = 0; is < 2; ++is) {
          acc[is][jn] = __builtin_amdgcn_mfma_f32_16x16x32_bf16(ah[is][kh], bh[jn], acc[is][jn], 0, 0, 0);
          acc[is][jn] = __builtin_amdgcn_mfma_f32_16x16x32_bf16(ah[is][kh], bl[jn], acc[is][jn], 0, 0, 0);
          acc[is][jn] = __builtin_amdgcn_mfma_f32_16x16x32_bf16(al[is][kh], bh[jn], acc[is][jn], 0, 0, 0);
        }
    }

    // epilogue: d2 = sqi + sqj - 2*dot -> S
    #pragma unroll
    for (int jn = 0; jn < 4; ++jn) {
      float sqjv = sqj[jn*16 + m];
      #pragma unroll
      for (int is = 0; is < 2; ++is)
        #pragma unroll
        for (int r = 0; r < 4; ++r) {
          int row = (2*w + is)*16 + quad*4 + r;
          S[row*65 + jn*16 + m] = sqi_v[is][r] + sqjv - 2.f*acc[is][jn][r];
        }
    }
    __syncthreads();                       // S(c) complete; B(c) free

    int jg0 = jbase + c*64 + shalf*32;
    const float* srp = S + srow*65 + shalf*32;
    for (int i = 0; i < 32; ++i) {
      float d = srp[i];
      if (d < d7[6]) {                     // strict < : ascending j stable
        int jj = jg0 + i;
        int k = 6;
        #pragma unroll
        for (int t = 5; t >= 0; --t)
          if (d < d7[t]) { d7[t+1] = d7[t]; x7[t+1] = x7[t]; k = t; }
        d7[k] = d; x7[k] = jj;
      }
    }
    if (c < 7) stageB(c + 1);
  }

  // level-1 merge: 2 threads/row -> 7 per (row, split)
  __syncthreads();
  float* cd = S;                 // [128][14]
  int*   ci = (int*)Bh;         // [128][14] (fits: 1792 ints <= 2304)
  #pragma unroll
  for (int k = 0; k < 7; ++k) {
    cd[srow*14 + shalf*7 + k] = d7[k];
    ci[srow*14 + shalf*7 + k] = x7[k];
  }
  __syncthreads();
  if (tid < 128) {
    float md[7]; int mi[7];
    #pragma unroll
    for (int k = 0; k < 7; ++k) { md[k] = 3.0e38f; mi[k] = 0x7fffffff; }
    for (int e = 0; e < 14; ++e) {
      float d = cd[tid*14 + e]; int jj = ci[tid*14 + e];
      if (d < md[6] || (d == md[6] && jj < mi[6])) {
        int k = 6;
        #pragma unroll
        for (int t = 5; t >= 0; --t)
          if (d < md[t] || (d == md[t] && jj < mi[t])) { md[t+1] = md[t]; mi[t+1] = mi[t]; k = t; }
        md[k] = d; mi[k] = jj;
      }
    }
    int g = b*NN + i0 + tid;
    int base = (g*NCH + jsp)*7;
    #pragma unroll
    for (int k = 0; k < 7; ++k) { pd[base+k] = md[k]; pidx[base+k] = mi[k]; }
  }
}

// ---------------- K3: merge per-split top7 -> final 7 neighbors --------------
__global__ __launch_bounds__(256) void k_merge(const float* __restrict__ pd,
                                               const int* __restrict__ pidx,
                                               int* __restrict__ nbr) {
  int g = blockIdx.x*256 + threadIdx.x;    // 0..8191
  float d7[7]; int x7[7];
  #pragma unroll
  for (int k = 0; k < 7; ++k) { d7[k] = 3.0e38f; x7[k] = 0x7fffffff; }
  int base = g*NCH*7;
  for (int e = 0; e < NCH*7; ++e) {        // splits ascending => j ascending
    float d = pd[base+e]; int jj = pidx[base+e];
    if (d < d7[6]) {
      int k = 6;
      #pragma unroll
      for (int t = 5; t >= 0; --t) {
        if (d < d7[t]) { d7[t+1] = d7[t]; x7[t+1] = x7[t]; k = t; }
      }
      d7[k] = d; x7[k] = jj;
    }
  }
  #pragma unroll
  for (int k = 0; k < 7; ++k) nbr[g*7 + k] = x7[k];
}

// ---------------- K4: hcat = yn @ [W0|W1] -----------------------------------
__global__ __launch_bounds__(256) void k_hcat(const float* __restrict__ yn,
                                              const float* __restrict__ W0,
                                              const float* __restrict__ W1,
                                              float* __restrict__ hcat) {
  __shared__ float Ws[64*128];
  __shared__ float yt[16*64];
  int b = blockIdx.x >> 8, n0 = (blockIdx.x & 255)*16;
  int tid = threadIdx.x;
  for (int idx = tid; idx < 8192; idx += 256) {
    int k = idx >> 7, c = idx & 127;
    Ws[idx] = (c < 64) ? W0[k*64 + c] : W1[k*64 + (c - 64)];
  }
  {
    const float4* src = (const float4*)(yn + (b*NN + n0)*64);
    for (int idx = tid; idx < 256; idx += 256) ((float4*)yt)[idx] = src[idx];
  }
  __syncthreads();
  int c = tid & 127, nh = tid >> 7;
  for (int nn = 0; nn < 8; ++nn) {
    int node = nh*8 + nn;
    const float* yr = yt + node*64;
    float acc = 0.f;
    #pragma unroll
    for (int k = 0; k < 64; ++k) acc += yr[k] * Ws[k*128 + c];
    hcat[(b*NN + n0 + node)*128 + c] = acc;
  }
}

// ---------------- K5: f-vectors layer1 --------------------------------------
__global__ __launch_bounds__(256) void k_fv1(const float* __restrict__ hcat,
                                             const float* __restrict__ a0,
                                             const float* __restrict__ a1,
                                             float* __restrict__ fv) {
  int lane = threadIdx.x & 63, wv = threadIdx.x >> 6;
  int g = blockIdx.x*4 + wv;
  const float* hr = hcat + g*128;
  float h0 = hr[lane], h1 = hr[64 + lane];
  float s00 = h0*a0[lane], s01 = h0*a0[64+lane];
  float s10 = h1*a1[lane], s11 = h1*a1[64+lane];
  #pragma unroll
  for (int off = 32; off > 0; off >>= 1) {
    s00 += __shfl_xor(s00, off); s01 += __shfl_xor(s01, off);
    s10 += __shfl_xor(s10, off); s11 += __shfl_xor(s11, off);
  }
  if (lane == 0) {
    fv[g] = s00; fv[8192 + g] = s01; fv[16384 + g] = s10; fv[24576 + g] = s11;
  }
}

// ---------------- K6: GAT layer1 aggregation (2 heads) + relu ---------------
__global__ __launch_bounds__(128) void k_agg1(const float* __restrict__ hcat,
                                              const float* __restrict__ fv,
                                              const int* __restrict__ nbr,
                                              float* __restrict__ hagg) {
  int g = blockIdx.x, c = threadIdx.x;
  int b = g >> 12;
  int head = c >> 6;
  int jj[7];
  #pragma unroll
  for (int t = 0; t < 7; ++t) jj[t] = nbr[g*7 + t];
  float f1 = fv[head*16384 + g];
  const float* f2p = fv + head*16384 + 8192 + (b << 12);
  float e[7], mx = -3.0e38f;
  #pragma unroll
  for (int t = 0; t < 7; ++t) {
    float v = f1 + f2p[jj[t]];
    v = (v >= 0.f) ? v : 0.2f*v;
    e[t] = v; mx = fmaxf(mx, v);
  }
  float wgt[7], s = 0.f;
  #pragma unroll
  for (int t = 0; t < 7; ++t) { wgt[t] = expf(e[t] - mx); s += wgt[t]; }
  float acc = 0.f;
  #pragma unroll
  for (int t = 0; t < 7; ++t)
    acc += (wgt[t]/s) * hcat[((b << 12) + jj[t])*128 + c];
  hagg[g*128 + c] = fmaxf(acc, 0.f);
}

// ---------------- K7: ho = hagg @ W_out -------------------------------------
__global__ __launch_bounds__(256) void k_ho(const float* __restrict__ hagg,
                                            const float* __restrict__ Wout,
                                            float* __restrict__ ho) {
  __shared__ float Ws[128*64];
  __shared__ float ht[16*128];
  int b = blockIdx.x >> 8, n0 = (blockIdx.x & 255)*16;
  int tid = threadIdx.x;
  for (int idx = tid; idx < 8192; idx += 256) Ws[idx] = Wout[idx];
  {
    const float4* src = (const float4*)(hagg + (b*NN + n0)*128);
    for (int idx = tid; idx < 512; idx += 256) ((float4*)ht)[idx] = src[idx];
  }
  __syncthreads();
  int c = tid & 63, ngrp = tid >> 6;
  for (int nn = 0; nn < 4; ++nn) {
    int node = ngrp*4 + nn;
    const float* hr = ht + node*128;
    float acc = 0.f;
    #pragma unroll
    for (int k = 0; k < 128; ++k) acc += hr[k] * Ws[k*64 + c];
    ho[(b*NN + n0 + node)*64 + c] = acc;
  }
}

// ---------------- K8: f-vectors layer2 --------------------------------------
__global__ __launch_bounds__(256) void k_fv2(const float* __restrict__ ho,
                                             const float* __restrict__ aout,
                                             float* __restrict__ fo) {
  int lane = threadIdx.x & 63, wv = threadIdx.x >> 6;
  int g = blockIdx.x*4 + wv;
  float v = ho[g*64 + lane];
  float s0 = v*aout[lane], s1 = v*aout[64+lane];
  #pragma unroll
  for (int off = 32; off > 0; off >>= 1) {
    s0 += __shfl_xor(s0, off); s1 += __shfl_xor(s1, off);
  }
  if (lane == 0) { fo[g] = s0; fo[8192 + g] = s1; }
}

// ---------------- K9: layer2 agg + elu + log_softmax ------------------------
__global__ __launch_bounds__(64) void k_agg2(const float* __restrict__ ho,
                                             const float* __restrict__ fo,
                                             const int* __restrict__ nbr,
                                             float* __restrict__ zbuf) {
  int g = blockIdx.x, c = threadIdx.x;
  int b = g >> 12;
  int jj[7];
  #pragma unroll
  for (int t = 0; t < 7; ++t) jj[t] = nbr[g*7 + t];
  float f1 = fo[g];
  const float* f2p = fo + 8192 + (b << 12);
  float e[7], mx = -3.0e38f;
  #pragma unroll
  for (int t = 0; t < 7; ++t) {
    float v = f1 + f2p[jj[t]];
    v = (v >= 0.f) ? v : 0.2f*v;
    e[t] = v; mx = fmaxf(mx, v);
  }
  float wgt[7], s = 0.f;
  #pragma unroll
  for (int t = 0; t < 7; ++t) { wgt[t] = expf(e[t] - mx); s += wgt[t]; }
  float acc = 0.f;
  #pragma unroll
  for (int t = 0; t < 7; ++t)
    acc += (wgt[t]/s) * ho[((b << 12) + jj[t])*64 + c];
  float v = (acc > 0.f) ? acc : expm1f(acc);        // elu
  float mm = v;
  #pragma unroll
  for (int off = 32; off > 0; off >>= 1) mm = fmaxf(mm, __shfl_xor(mm, off));
  float ex = expf(v - mm), ss = ex;
  #pragma unroll
  for (int off = 32; off > 0; off >>= 1) ss += __shfl_xor(ss, off);
  zbuf[g*64 + c] = v - mm - logf(ss);
}

// ---------------- K10: ConvTranspose2d (64->64, k3 s2 p1 op1) ---------------
__global__ __launch_bounds__(256) void k_convt(const float* __restrict__ z,
                                               const float* __restrict__ wT,
                                               const float* __restrict__ bias,
                                               float* __restrict__ out) {
  int b = blockIdx.z, oy = blockIdx.y, ox0 = blockIdx.x * 16;
  int co = threadIdx.x & 63, p = threadIdx.x >> 6;
  int iy[2], kyv[2], nty;
  if (!(oy & 1)) { iy[0] = oy >> 1; kyv[0] = 1; nty = 1; }
  else {
    iy[0] = (oy - 1) >> 1; kyv[0] = 2; nty = 1;
    int i0 = (oy + 1) >> 1;
    if (i0 < 64) { iy[1] = i0; kyv[1] = 0; nty = 2; }
  }
  float bv = bias[co];
  float accs[4];
  for (int gg = 0; gg < 4; ++gg) {
    int ox = ox0 + gg*4 + p;
    int ix[2], kxv[2], ntx;
    if (!(ox & 1)) { ix[0] = ox >> 1; kxv[0] = 1; ntx = 1; }
    else {
      ix[0] = (ox - 1) >> 1; kxv[0] = 2; ntx = 1;
      int i0 = (ox + 1) >> 1;
      if (i0 < 64) { ix[1] = i0; kxv[1] = 0; ntx = 2; }
    }
    float acc = bv;
    for (int ty = 0; ty < nty; ++ty)
      for (int tx = 0; tx < ntx; ++tx) {
        const float* zr = z + ((b << 12) + iy[ty]*64 + ix[tx])*64;
        const float* wr = wT + (kyv[ty]*3 + kxv[tx])*4096 + co;
        float a = 0.f;
        #pragma unroll 8
        for (int ci = 0; ci < 64; ++ci) a += zr[ci] * wr[ci << 6];
        acc += a;
      }
    accs[gg] = acc;
  }
  __shared__ float st[1024];
  for (int gg = 0; gg < 4; ++gg) st[co*16 + gg*4 + p] = accs[gg];
  __syncthreads();
  for (int idx = threadIdx.x; idx < 1024; idx += 256) {
    int cc = idx >> 4, oxo = idx & 15;
    out[((b*64 + cc)*128 + oy)*128 + ox0 + oxo] = st[idx];
  }
}

// ---------------- launch ----------------------------------------------------
extern "C" void kernel_launch(void* const* d_in, const int* in_sizes, int n_in,
                              void* d_out, int out_size, void* d_ws, size_t ws_size,
                              hipStream_t stream) {
  const float* x      = (const float*)d_in[0];
  const float* w_head = (const float*)d_in[1];
  const float* b_head = (const float*)d_in[2];
  const float* W0     = (const float*)d_in[3];
  const float* a0     = (const float*)d_in[4];
  const float* W1     = (const float*)d_in[5];
  const float* a1     = (const float*)d_in[6];
  const float* W_out  = (const float*)d_in[7];
  const float* a_out  = (const float*)d_in[8];
  const float* w_last = (const float*)d_in[9];
  const float* b_last = (const float*)d_in[10];
  float* out = (float*)d_out;

  float* wsf = (float*)d_ws;
  int*   wsi = (int*)d_ws;
  float* yn   = wsf + OF_YN;
  float* sq   = wsf + OF_SQ;
  float* hcat = wsf + OF_HCAT;
  float* fv   = wsf + OF_FV;
  float* hagg = wsf + OF_HAGG;
  float* ho   = wsf + OF_HO;
  float* fo   = wsf + OF_FO;
  float* zbuf = wsf + OF_Z;
  float* pd   = wsf + OF_PD;
  int*   pidx = wsi + OF_PI;
  int*   nbr  = wsi + OF_NBR;
  float* wT   = wsf + OF_WT;
  float* whT  = wsf + OF_WHT;
  unsigned short* ynh = (unsigned short*)(wsf + OF_YNH);
  unsigned short* ynl = (unsigned short*)(wsf + OF_YNL);

  hipLaunchKernelGGL(k_prep,  dim3(214), dim3(256), 0, stream, w_last, w_head, wT, whT);
  hipLaunchKernelGGL(k_head,  dim3(256), dim3(256), 0, stream, x, whT, b_head, yn, sq, ynh, ynl);
  hipLaunchKernelGGL(k_knn2,  dim3(32, NCH, 2), dim3(256), 0, stream, ynh, ynl, sq, pd, pidx);
  hipLaunchKernelGGL(k_merge, dim3(32), dim3(256), 0, stream, pd, pidx, nbr);
  hipLaunchKernelGGL(k_hcat,  dim3(512), dim3(256), 0, stream, yn, W0, W1, hcat);
  hipLaunchKernelGGL(k_fv1,   dim3(2048), dim3(256), 0, stream, hcat, a0, a1, fv);
  hipLaunchKernelGGL(k_agg1,  dim3(8192), dim3(128), 0, stream, hcat, fv, nbr, hagg);
  hipLaunchKernelGGL(k_ho,    dim3(512), dim3(256), 0, stream, hagg, W_out, ho);
  hipLaunchKernelGGL(k_fv2,   dim3(2048), dim3(256), 0, stream, ho, a_out, fo);
  hipLaunchKernelGGL(k_agg2,  dim3(8192), dim3(64), 0, stream, ho, fo, nbr, zbuf);
  hipLaunchKernelGGL(k_convt, dim3(8, 128, 2), dim3(256), 0, stream, zbuf, wT, b_last, out);
}

// Round 3
// 280.814 us; speedup vs baseline: 1.3867x; 1.1878x over previous
//
#include <hip/hip_runtime.h>
#include <math.h>

// Problem constants
#define B2     2
#define CIN    31
#define CC     64      // conv out channels / GAT dim
#define NN     4096    // 64*64 nodes
#define NCH    8       // kNN j-splits (512 j each)

typedef short bf16x8 __attribute__((ext_vector_type(8)));
typedef float f32x4  __attribute__((ext_vector_type(4)));

__device__ inline unsigned short f2bf(float f) {
  union { float f; unsigned u; } v; v.f = f;
  unsigned r = (v.u + 0x7fffu + ((v.u >> 16) & 1u)) >> 16;
  return (unsigned short)r;
}
__device__ inline float bf2f(unsigned short h) {
  union { float f; unsigned u; } v; v.u = ((unsigned)h) << 16;
  return v.f;
}

// ---------------- workspace layout (in 4-byte elements) ----------------
constexpr int OF_YN   = 0;                         // [B,N,64] fp32
constexpr int OF_SQ   = OF_YN   + B2*NN*CC;        // [B,N]
constexpr int OF_HCAT = OF_SQ   + B2*NN;           // [B,N,128]
constexpr int OF_FV   = OF_HCAT + B2*NN*128;       // 4 x [B*N]
constexpr int OF_HAGG = OF_FV   + 4*B2*NN;         // [B,N,128]
constexpr int OF_HO   = OF_HAGG + B2*NN*128;       // [B,N,64]
constexpr int OF_FO   = OF_HO   + B2*NN*CC;        // 2 x [B*N]
constexpr int OF_Z    = OF_FO   + 2*B2*NN;         // [B,N,64]
constexpr int OF_PD   = OF_Z    + B2*NN*CC;        // partial top7 dists [B*N][NCH][7]
constexpr int OF_PI   = OF_PD   + B2*NN*NCH*7;     // partial top7 idx (int)
constexpr int OF_NBR  = OF_PI   + B2*NN*NCH*7;     // [B*N][7] neighbor idx (int)
constexpr int OF_WT   = OF_NBR  + B2*NN*7;         // convT weights [9][64][64]
constexpr int OF_WHT  = OF_WT   + 9*64*64;         // head conv weights [279][64]
constexpr int OF_YNH  = OF_WHT  + 279*64;          // bf16 hi [B,N,64] (ushort)
constexpr int OF_YNL  = OF_YNH  + B2*NN*CC/2;      // bf16 lo [B,N,64] (ushort)
// end ~= 21.1 MB

// ---------------- K0: weight transposes ----------------
__global__ __launch_bounds__(256) void k_prep(const float* __restrict__ wlast,
                                              const float* __restrict__ whead,
                                              float* __restrict__ wT,
                                              float* __restrict__ whT) {
  int idx = blockIdx.x*256 + threadIdx.x;
  if (idx < 36864) {
    int co = idx & 63, ci = (idx >> 6) & 63, kk = idx >> 12;
    wT[idx] = wlast[(ci*64 + co)*9 + kk];
  } else if (idx < 36864 + 279*64) {
    int j = idx - 36864;
    int c = j & 63, q = j >> 6;
    whT[j] = whead[c*279 + q];
  }
}

// ---------------- K1: head conv (31->64, k3 s2 p1) + sq + bf16 split --------
__global__ __launch_bounds__(256) void k_head(const float* __restrict__ x,
                                              const float* __restrict__ whT,
                                              const float* __restrict__ bias,
                                              float* __restrict__ yn,
                                              float* __restrict__ sq,
                                              unsigned short* __restrict__ ynh,
                                              unsigned short* __restrict__ ynl) {
  int lane = threadIdx.x & 63, wv = threadIdx.x >> 6;
  int gbase = blockIdx.x*32 + wv*8;
  __shared__ float patch[4][8][280];
  for (int nn = 0; nn < 8; ++nn) {
    int g = gbase + nn;
    int b = g >> 12, n = g & 4095;
    int oh = n >> 6, ow = n & 63;
    for (int q = lane; q < 279; q += 64) {
      int ci = q / 9, r = q - ci*9;
      int ky = r / 3, kx = r - ky*3;
      int ih = 2*oh - 1 + ky, iw = 2*ow - 1 + kx;
      float v = 0.f;
      if (ih >= 0 && ih < 128 && iw >= 0 && iw < 128)
        v = x[((b*CIN + ci)*128 + ih)*128 + iw];
      patch[wv][nn][q] = v;
    }
  }
  __syncthreads();
  int c = lane;
  float acc[8];
  float bv = bias[c];
  #pragma unroll
  for (int nn = 0; nn < 8; ++nn) acc[nn] = bv;
  for (int q = 0; q < 279; ++q) {
    float wgt = whT[q*64 + c];
    #pragma unroll
    for (int nn = 0; nn < 8; ++nn) acc[nn] += patch[wv][nn][q] * wgt;
  }
  for (int nn = 0; nn < 8; ++nn) {
    int g = gbase + nn;
    float y = acc[nn];
    yn[g*64 + c] = y;
    unsigned short hb = f2bf(y);
    ynh[g*64 + c] = hb;
    ynl[g*64 + c] = f2bf(y - bf2f(hb));
    float s = y*y;
    #pragma unroll
    for (int off = 32; off > 0; off >>= 1) s += __shfl_xor(s, off);
    if (lane == 0) sq[g] = s;
  }
}

// ---------------- K2: MFMA split-bf16 Gram + fused top-7 --------------------
__global__ __launch_bounds__(256, 2) void k_knn2(const unsigned short* __restrict__ ynh,
                                                 const unsigned short* __restrict__ ynl,
                                                 const float* __restrict__ sq,
                                                 float* __restrict__ pd,
                                                 int* __restrict__ pidx) {
  __shared__ unsigned short Bh[64*72];
  __shared__ unsigned short Bl[64*72];
  __shared__ float S[128*65];
  __shared__ float sqj[64];

  int b = blockIdx.z, ib = blockIdx.x, jsp = blockIdx.y;
  int i0 = ib*128;
  int jbase = jsp*512;
  int tid = threadIdx.x;
  int lane = tid & 63, w = tid >> 6;
  int quad = lane >> 4, m = lane & 15;

  const unsigned short* ynh_b = ynh + (size_t)b*NN*64;
  const unsigned short* ynl_b = ynl + (size_t)b*NN*64;

  bf16x8 ah[2][2], al[2][2];
  float sqi_v[2][4];
  #pragma unroll
  for (int is = 0; is < 2; ++is) {
    int row = i0 + (2*w + is)*16 + m;
    ah[is][0] = *(const bf16x8*)(ynh_b + row*64 + quad*8);
    ah[is][1] = *(const bf16x8*)(ynh_b + row*64 + 32 + quad*8);
    al[is][0] = *(const bf16x8*)(ynl_b + row*64 + quad*8);
    al[is][1] = *(const bf16x8*)(ynl_b + row*64 + 32 + quad*8);
    #pragma unroll
    for (int r = 0; r < 4; ++r)
      sqi_v[is][r] = sq[b*NN + i0 + (2*w + is)*16 + quad*4 + r];
  }

  float d7[7]; int x7[7];
  #pragma unroll
  for (int k = 0; k < 7; ++k) { d7[k] = 3.0e38f; x7[k] = 0x7fffffff; }
  int srow = tid >> 1, shalf = tid & 1;

  auto stageB = [&](int c) {
    int jt = jbase + c*64;
    #pragma unroll
    for (int r2 = 0; r2 < 2; ++r2) {
      int row = (tid >> 3) + 32*r2, oct = tid & 7;
      *(uint4*)&Bh[row*72 + oct*8] = *(const uint4*)(ynh_b + (jt + row)*64 + oct*8);
      *(uint4*)&Bl[row*72 + oct*8] = *(const uint4*)(ynl_b + (jt + row)*64 + oct*8);
    }
    if (tid < 64) sqj[tid] = sq[b*NN + jt + tid];
  };

  stageB(0);

  for (int c = 0; c < 8; ++c) {
    __syncthreads();
    f32x4 acc[2][4];
    #pragma unroll
    for (int is = 0; is < 2; ++is)
      #pragma unroll
      for (int jn = 0; jn < 4; ++jn)
        acc[is][jn] = (f32x4){0.f, 0.f, 0.f, 0.f};

    #pragma unroll
    for (int kh = 0; kh < 2; ++kh) {
      bf16x8 bh[4], bl[4];
      #pragma unroll
      for (int jn = 0; jn < 4; ++jn) {
        bh[jn] = *(const bf16x8*)&Bh[(jn*16 + m)*72 + kh*32 + quad*8];
        bl[jn] = *(const bf16x8*)&Bl[(jn*16 + m)*72 + kh*32 + quad*8];
      }
      #pragma unroll
      for (int jn = 0; jn < 4; ++jn)
        #pragma unroll
        for (int is = 0; is < 2; ++is) {
          acc[is][jn] = __builtin_amdgcn_mfma_f32_16x16x32_bf16(ah[is][kh], bh[jn], acc[is][jn], 0, 0, 0);
          acc[is][jn] = __builtin_amdgcn_mfma_f32_16x16x32_bf16(ah[is][kh], bl[jn], acc[is][jn], 0, 0, 0);
          acc[is][jn] = __builtin_amdgcn_mfma_f32_16x16x32_bf16(al[is][kh], bh[jn], acc[is][jn], 0, 0, 0);
        }
    }

    #pragma unroll
    for (int jn = 0; jn < 4; ++jn) {
      float sqjv = sqj[jn*16 + m];
      #pragma unroll
      for (int is = 0; is < 2; ++is)
        #pragma unroll
        for (int r = 0; r < 4; ++r) {
          int row = (2*w + is)*16 + quad*4 + r;
          S[row*65 + jn*16 + m] = sqi_v[is][r] + sqjv - 2.f*acc[is][jn][r];
        }
    }
    __syncthreads();

    int jg0 = jbase + c*64 + shalf*32;
    const float* srp = S + srow*65 + shalf*32;
    for (int i = 0; i < 32; ++i) {
      float d = srp[i];
      if (d < d7[6]) {
        int jj = jg0 + i;
        int k = 6;
        #pragma unroll
        for (int t = 5; t >= 0; --t)
          if (d < d7[t]) { d7[t+1] = d7[t]; x7[t+1] = x7[t]; k = t; }
        d7[k] = d; x7[k] = jj;
      }
    }
    if (c < 7) stageB(c + 1);
  }

  __syncthreads();
  float* cd = S;
  int*   ci = (int*)Bh;
  #pragma unroll
  for (int k = 0; k < 7; ++k) {
    cd[srow*14 + shalf*7 + k] = d7[k];
    ci[srow*14 + shalf*7 + k] = x7[k];
  }
  __syncthreads();
  if (tid < 128) {
    float md[7]; int mi[7];
    #pragma unroll
    for (int k = 0; k < 7; ++k) { md[k] = 3.0e38f; mi[k] = 0x7fffffff; }
    for (int e = 0; e < 14; ++e) {
      float d = cd[tid*14 + e]; int jj = ci[tid*14 + e];
      if (d < md[6] || (d == md[6] && jj < mi[6])) {
        int k = 6;
        #pragma unroll
        for (int t = 5; t >= 0; --t)
          if (d < md[t] || (d == md[t] && jj < mi[t])) { md[t+1] = md[t]; mi[t+1] = mi[t]; k = t; }
        md[k] = d; mi[k] = jj;
      }
    }
    int g = b*NN + i0 + tid;
    int base = (g*NCH + jsp)*7;
    #pragma unroll
    for (int k = 0; k < 7; ++k) { pd[base+k] = md[k]; pidx[base+k] = mi[k]; }
  }
}

// ---------------- K3: merge per-split top7 -> final 7 neighbors --------------
__global__ __launch_bounds__(256) void k_merge(const float* __restrict__ pd,
                                               const int* __restrict__ pidx,
                                               int* __restrict__ nbr) {
  int g = blockIdx.x*256 + threadIdx.x;
  float d7[7]; int x7[7];
  #pragma unroll
  for (int k = 0; k < 7; ++k) { d7[k] = 3.0e38f; x7[k] = 0x7fffffff; }
  int base = g*NCH*7;
  for (int e = 0; e < NCH*7; ++e) {
    float d = pd[base+e]; int jj = pidx[base+e];
    if (d < d7[6]) {
      int k = 6;
      #pragma unroll
      for (int t = 5; t >= 0; --t) {
        if (d < d7[t]) { d7[t+1] = d7[t]; x7[t+1] = x7[t]; k = t; }
      }
      d7[k] = d; x7[k] = jj;
    }
  }
  #pragma unroll
  for (int k = 0; k < 7; ++k) nbr[g*7 + k] = x7[k];
}

// ---------------- K4: hcat = yn @ [W0|W1] -----------------------------------
__global__ __launch_bounds__(256) void k_hcat(const float* __restrict__ yn,
                                              const float* __restrict__ W0,
                                              const float* __restrict__ W1,
                                              float* __restrict__ hcat) {
  __shared__ float Ws[64*128];
  __shared__ float yt[16*64];
  int b = blockIdx.x >> 8, n0 = (blockIdx.x & 255)*16;
  int tid = threadIdx.x;
  for (int idx = tid; idx < 8192; idx += 256) {
    int k = idx >> 7, c = idx & 127;
    Ws[idx] = (c < 64) ? W0[k*64 + c] : W1[k*64 + (c - 64)];
  }
  {
    const float4* src = (const float4*)(yn + (b*NN + n0)*64);
    for (int idx = tid; idx < 256; idx += 256) ((float4*)yt)[idx] = src[idx];
  }
  __syncthreads();
  int c = tid & 127, nh = tid >> 7;
  for (int nn = 0; nn < 8; ++nn) {
    int node = nh*8 + nn;
    const float* yr = yt + node*64;
    float acc = 0.f;
    #pragma unroll
    for (int k = 0; k < 64; ++k) acc += yr[k] * Ws[k*128 + c];
    hcat[(b*NN + n0 + node)*128 + c] = acc;
  }
}

// ---------------- K5: f-vectors layer1 --------------------------------------
__global__ __launch_bounds__(256) void k_fv1(const float* __restrict__ hcat,
                                             const float* __restrict__ a0,
                                             const float* __restrict__ a1,
                                             float* __restrict__ fv) {
  int lane = threadIdx.x & 63, wv = threadIdx.x >> 6;
  int g = blockIdx.x*4 + wv;
  const float* hr = hcat + g*128;
  float h0 = hr[lane], h1 = hr[64 + lane];
  float s00 = h0*a0[lane], s01 = h0*a0[64+lane];
  float s10 = h1*a1[lane], s11 = h1*a1[64+lane];
  #pragma unroll
  for (int off = 32; off > 0; off >>= 1) {
    s00 += __shfl_xor(s00, off); s01 += __shfl_xor(s01, off);
    s10 += __shfl_xor(s10, off); s11 += __shfl_xor(s11, off);
  }
  if (lane == 0) {
    fv[g] = s00; fv[8192 + g] = s01; fv[16384 + g] = s10; fv[24576 + g] = s11;
  }
}

// ---------------- K6: GAT layer1 aggregation (2 heads) + relu ---------------
__global__ __launch_bounds__(128) void k_agg1(const float* __restrict__ hcat,
                                              const float* __restrict__ fv,
                                              const int* __restrict__ nbr,
                                              float* __restrict__ hagg) {
  int g = blockIdx.x, c = threadIdx.x;
  int b = g >> 12;
  int head = c >> 6;
  int jj[7];
  #pragma unroll
  for (int t = 0; t < 7; ++t) jj[t] = nbr[g*7 + t];
  float f1 = fv[head*16384 + g];
  const float* f2p = fv + head*16384 + 8192 + (b << 12);
  float e[7], mx = -3.0e38f;
  #pragma unroll
  for (int t = 0; t < 7; ++t) {
    float v = f1 + f2p[jj[t]];
    v = (v >= 0.f) ? v : 0.2f*v;
    e[t] = v; mx = fmaxf(mx, v);
  }
  float wgt[7], s = 0.f;
  #pragma unroll
  for (int t = 0; t < 7; ++t) { wgt[t] = expf(e[t] - mx); s += wgt[t]; }
  float acc = 0.f;
  #pragma unroll
  for (int t = 0; t < 7; ++t)
    acc += (wgt[t]/s) * hcat[((b << 12) + jj[t])*128 + c];
  hagg[g*128 + c] = fmaxf(acc, 0.f);
}

// ---------------- K7: ho = hagg @ W_out -------------------------------------
__global__ __launch_bounds__(256) void k_ho(const float* __restrict__ hagg,
                                            const float* __restrict__ Wout,
                                            float* __restrict__ ho) {
  __shared__ float Ws[128*64];
  __shared__ float ht[16*128];
  int b = blockIdx.x >> 8, n0 = (blockIdx.x & 255)*16;
  int tid = threadIdx.x;
  for (int idx = tid; idx < 8192; idx += 256) Ws[idx] = Wout[idx];
  {
    const float4* src = (const float4*)(hagg + (b*NN + n0)*128);
    for (int idx = tid; idx < 512; idx += 256) ((float4*)ht)[idx] = src[idx];
  }
  __syncthreads();
  int c = tid & 63, ngrp = tid >> 6;
  for (int nn = 0; nn < 4; ++nn) {
    int node = ngrp*4 + nn;
    const float* hr = ht + node*128;
    float acc = 0.f;
    #pragma unroll
    for (int k = 0; k < 128; ++k) acc += hr[k] * Ws[k*64 + c];
    ho[(b*NN + n0 + node)*64 + c] = acc;
  }
}

// ---------------- K8: f-vectors layer2 --------------------------------------
__global__ __launch_bounds__(256) void k_fv2(const float* __restrict__ ho,
                                             const float* __restrict__ aout,
                                             float* __restrict__ fo) {
  int lane = threadIdx.x & 63, wv = threadIdx.x >> 6;
  int g = blockIdx.x*4 + wv;
  float v = ho[g*64 + lane];
  float s0 = v*aout[lane], s1 = v*aout[64+lane];
  #pragma unroll
  for (int off = 32; off > 0; off >>= 1) {
    s0 += __shfl_xor(s0, off); s1 += __shfl_xor(s1, off);
  }
  if (lane == 0) { fo[g] = s0; fo[8192 + g] = s1; }
}

// ---------------- K9: layer2 agg + elu + log_softmax ------------------------
__global__ __launch_bounds__(64) void k_agg2(const float* __restrict__ ho,
                                             const float* __restrict__ fo,
                                             const int* __restrict__ nbr,
                                             float* __restrict__ zbuf) {
  int g = blockIdx.x, c = threadIdx.x;
  int b = g >> 12;
  int jj[7];
  #pragma unroll
  for (int t = 0; t < 7; ++t) jj[t] = nbr[g*7 + t];
  float f1 = fo[g];
  const float* f2p = fo + 8192 + (b << 12);
  float e[7], mx = -3.0e38f;
  #pragma unroll
  for (int t = 0; t < 7; ++t) {
    float v = f1 + f2p[jj[t]];
    v = (v >= 0.f) ? v : 0.2f*v;
    e[t] = v; mx = fmaxf(mx, v);
  }
  float wgt[7], s = 0.f;
  #pragma unroll
  for (int t = 0; t < 7; ++t) { wgt[t] = expf(e[t] - mx); s += wgt[t]; }
  float acc = 0.f;
  #pragma unroll
  for (int t = 0; t < 7; ++t)
    acc += (wgt[t]/s) * ho[((b << 12) + jj[t])*64 + c];
  float v = (acc > 0.f) ? acc : expm1f(acc);
  float mm = v;
  #pragma unroll
  for (int off = 32; off > 0; off >>= 1) mm = fmaxf(mm, __shfl_xor(mm, off));
  float ex = expf(v - mm), ss = ex;
  #pragma unroll
  for (int off = 32; off > 0; off >>= 1) ss += __shfl_xor(ss, off);
  zbuf[g*64 + c] = v - mm - logf(ss);
}

// ---------------- K10: ConvTranspose2d v2 — per-row tap-looped LDS matmul ---
// grid (128 oy, 2 b), 256 threads. Block computes one full output row:
// [64 co][128 ox]. Weights staged per tap (16KB), z rows staged transposed.
__global__ __launch_bounds__(256) void k_convt2(const float* __restrict__ z,
                                                const float* __restrict__ wT,
                                                const float* __restrict__ bias,
                                                float* __restrict__ out) {
  __shared__ __align__(16) float lds[12800];   // 51200 B
  float* zt = lds;              // [2 rows][64 ci][68]  (8704 floats)
  float* ws = lds + 8704;       // [64 ci][64 co]       (4096 floats)
  float* so = lds;              // [64 co][129] epilogue alias (8256 floats)

  int oy = blockIdx.x, b = blockIdx.y;
  int r = oy >> 1, pi = oy & 1;
  int tid = threadIdx.x;
  int colo = tid & 15, pgrp = tid >> 4;
  int co4 = colo*4, m0 = pgrp*4;

  // stage z rows (transposed, zero-padded at ix>=64 / iy>=64)
  int nrows = pi ? 2 : 1;
  for (int row = 0; row < nrows; ++row) {
    int iy = r + row;
    const float* zsrc = z + (((b << 12) + iy*64) << 6);
    for (int idx = tid; idx < 4352; idx += 256) {
      int ix = idx >> 6, ci = idx & 63;
      float v = 0.f;
      if (ix < 64 && iy < 64) v = zsrc[ix*64 + ci];
      zt[row*4352 + ci*68 + ix] = v;
    }
  }

  // acc[chi][k][cc]: parity class chi (ox even/odd), 4 pixels, 4 co
  float acc[2][4][4];
  {
    float4 bv = *(const float4*)&bias[co4];
    #pragma unroll
    for (int chi = 0; chi < 2; ++chi)
      #pragma unroll
      for (int k = 0; k < 4; ++k) {
        acc[chi][k][0] = bv.x; acc[chi][k][1] = bv.y;
        acc[chi][k][2] = bv.z; acc[chi][k][3] = bv.w;
      }
  }

  int kys[2], rows[2], nky;
  if (pi == 0) { kys[0] = 1; rows[0] = 0; nky = 1; }
  else         { kys[0] = 2; rows[0] = 0; kys[1] = 0; rows[1] = 1; nky = 2; }

  for (int t = 0; t < nky; ++t) {
    const float* zrow = zt + rows[t]*4352;
    for (int kx = 0; kx < 3; ++kx) {
      const float* wsrc = wT + (kys[t]*3 + kx)*4096;
      __syncthreads();
      for (int idx = tid; idx < 4096; idx += 256) ws[idx] = wsrc[idx];
      __syncthreads();
      int chi = (kx == 1) ? 0 : 1;
      int xoff = (kx == 0) ? 1 : 0;
      float* ap = &acc[chi][0][0];
      for (int ci = 0; ci < 64; ++ci) {
        float4 wv = *(const float4*)&ws[ci*64 + co4];
        const float* zp = zrow + ci*68 + m0;
        float4 zv;
        if (xoff == 0) {
          zv = *(const float4*)zp;
        } else {
          float4 a0 = *(const float4*)zp;
          float4 a1 = *(const float4*)(zp + 4);
          zv.x = a0.y; zv.y = a0.z; zv.z = a0.w; zv.w = a1.x;
        }
        #pragma unroll
        for (int k = 0; k < 4; ++k) {
          float zk = (&zv.x)[k];
          ap[k*4+0] += zk * wv.x;
          ap[k*4+1] += zk * wv.y;
          ap[k*4+2] += zk * wv.z;
          ap[k*4+3] += zk * wv.w;
        }
      }
    }
  }

  // epilogue: LDS transpose -> coalesced stores
  __syncthreads();
  #pragma unroll
  for (int chi = 0; chi < 2; ++chi)
    #pragma unroll
    for (int k = 0; k < 4; ++k)
      #pragma unroll
      for (int cc = 0; cc < 4; ++cc)
        so[(co4 + cc)*129 + 2*(m0 + k) + chi] = acc[chi][k][cc];
  __syncthreads();
  float* orow = out + (((b << 6))*128 + oy)*128;
  for (int idx = tid; idx < 8192; idx += 256) {
    int co = idx >> 7, ox = idx & 127;
    out[(((b << 6) + co)*128 + oy)*128 + ox] = so[co*129 + ox];
  }
}

// ---------------- launch ----------------------------------------------------
extern "C" void kernel_launch(void* const* d_in, const int* in_sizes, int n_in,
                              void* d_out, int out_size, void* d_ws, size_t ws_size,
                              hipStream_t stream) {
  const float* x      = (const float*)d_in[0];
  const float* w_head = (const float*)d_in[1];
  const float* b_head = (const float*)d_in[2];
  const float* W0     = (const float*)d_in[3];
  const float* a0     = (const float*)d_in[4];
  const float* W1     = (const float*)d_in[5];
  const float* a1     = (const float*)d_in[6];
  const float* W_out  = (const float*)d_in[7];
  const float* a_out  = (const float*)d_in[8];
  const float* w_last = (const float*)d_in[9];
  const float* b_last = (const float*)d_in[10];
  float* out = (float*)d_out;

  float* wsf = (float*)d_ws;
  int*   wsi = (int*)d_ws;
  float* yn   = wsf + OF_YN;
  float* sq   = wsf + OF_SQ;
  float* hcat = wsf + OF_HCAT;
  float* fv   = wsf + OF_FV;
  float* hagg = wsf + OF_HAGG;
  float* ho   = wsf + OF_HO;
  float* fo   = wsf + OF_FO;
  float* zbuf = wsf + OF_Z;
  float* pd   = wsf + OF_PD;
  int*   pidx = wsi + OF_PI;
  int*   nbr  = wsi + OF_NBR;
  float* wT   = wsf + OF_WT;
  float* whT  = wsf + OF_WHT;
  unsigned short* ynh = (unsigned short*)(wsf + OF_YNH);
  unsigned short* ynl = (unsigned short*)(wsf + OF_YNL);

  hipLaunchKernelGGL(k_prep,  dim3(214), dim3(256), 0, stream, w_last, w_head, wT, whT);
  hipLaunchKernelGGL(k_head,  dim3(256), dim3(256), 0, stream, x, whT, b_head, yn, sq, ynh, ynl);
  hipLaunchKernelGGL(k_knn2,  dim3(32, NCH, 2), dim3(256), 0, stream, ynh, ynl, sq, pd, pidx);
  hipLaunchKernelGGL(k_merge, dim3(32), dim3(256), 0, stream, pd, pidx, nbr);
  hipLaunchKernelGGL(k_hcat,  dim3(512), dim3(256), 0, stream, yn, W0, W1, hcat);
  hipLaunchKernelGGL(k_fv1,   dim3(2048), dim3(256), 0, stream, hcat, a0, a1, fv);
  hipLaunchKernelGGL(k_agg1,  dim3(8192), dim3(128), 0, stream, hcat, fv, nbr, hagg);
  hipLaunchKernelGGL(k_ho,    dim3(512), dim3(256), 0, stream, hagg, W_out, ho);
  hipLaunchKernelGGL(k_fv2,   dim3(2048), dim3(256), 0, stream, ho, a_out, fo);
  hipLaunchKernelGGL(k_agg2,  dim3(8192), dim3(64), 0, stream, ho, fo, nbr, zbuf);
  hipLaunchKernelGGL(k_convt2, dim3(128, 2), dim3(256), 0, stream, zbuf, wT, b_last, out);
}

// Round 4
// 269.924 us; speedup vs baseline: 1.4427x; 1.0403x over previous
//
#include <hip/hip_runtime.h>
#include <math.h>

// Problem constants
#define B2     2
#define CIN    31
#define CC     64      // conv out channels / GAT dim
#define NN     4096    // 64*64 nodes
#define NCH    8       // kNN j-splits (512 j each)

typedef short bf16x8 __attribute__((ext_vector_type(8)));
typedef float f32x4  __attribute__((ext_vector_type(4)));

__device__ inline unsigned short f2bf(float f) {
  union { float f; unsigned u; } v; v.f = f;
  unsigned r = (v.u + 0x7fffu + ((v.u >> 16) & 1u)) >> 16;
  return (unsigned short)r;
}
__device__ inline float bf2f(unsigned short h) {
  union { float f; unsigned u; } v; v.u = ((unsigned)h) << 16;
  return v.f;
}

// ---------------- workspace layout (in 4-byte elements) ----------------
constexpr int OF_YN   = 0;                         // [B,N,64] fp32
constexpr int OF_SQ   = OF_YN   + B2*NN*CC;        // [B,N]
constexpr int OF_HCAT = OF_SQ   + B2*NN;           // [B,N,128]
constexpr int OF_FV   = OF_HCAT + B2*NN*128;       // 4 x [B*N]
constexpr int OF_HAGG = OF_FV   + 4*B2*NN;         // [B,N,128]
constexpr int OF_HO   = OF_HAGG + B2*NN*128;       // [B,N,64]
constexpr int OF_FO   = OF_HO   + B2*NN*CC;        // 2 x [B*N]
constexpr int OF_Z    = OF_FO   + 2*B2*NN;         // [B,N,64]
constexpr int OF_PD   = OF_Z    + B2*NN*CC;        // partial top7 dists [B*N][NCH][7]
constexpr int OF_PI   = OF_PD   + B2*NN*NCH*7;     // partial top7 idx (int)
constexpr int OF_NBR  = OF_PI   + B2*NN*NCH*7;     // [B*N][7] neighbor idx (int)
constexpr int OF_WT   = OF_NBR  + B2*NN*7;         // convT weights [9][64][64]
constexpr int OF_WHT  = OF_WT   + 9*64*64;         // head conv weights [279][64]
constexpr int OF_YNH  = OF_WHT  + 279*64;          // bf16 hi [B,N,64] (ushort)
constexpr int OF_YNL  = OF_YNH  + B2*NN*CC/2;      // bf16 lo [B,N,64] (ushort)

// ---------------- K0: weight transposes ----------------
__global__ __launch_bounds__(256) void k_prep(const float* __restrict__ wlast,
                                              const float* __restrict__ whead,
                                              float* __restrict__ wT,
                                              float* __restrict__ whT) {
  int idx = blockIdx.x*256 + threadIdx.x;
  if (idx < 36864) {
    int co = idx & 63, ci = (idx >> 6) & 63, kk = idx >> 12;
    wT[idx] = wlast[(ci*64 + co)*9 + kk];
  } else if (idx < 36864 + 279*64) {
    int j = idx - 36864;
    int c = j & 63, q = j >> 6;
    whT[j] = whead[c*279 + q];
  }
}

// ---------------- K1: head conv (31->64, k3 s2 p1) + sq + bf16 split --------
__global__ __launch_bounds__(256) void k_head(const float* __restrict__ x,
                                              const float* __restrict__ whT,
                                              const float* __restrict__ bias,
                                              float* __restrict__ yn,
                                              float* __restrict__ sq,
                                              unsigned short* __restrict__ ynh,
                                              unsigned short* __restrict__ ynl) {
  int lane = threadIdx.x & 63, wv = threadIdx.x >> 6;
  int gbase = blockIdx.x*32 + wv*8;
  __shared__ float patch[4][8][280];
  for (int nn = 0; nn < 8; ++nn) {
    int g = gbase + nn;
    int b = g >> 12, n = g & 4095;
    int oh = n >> 6, ow = n & 63;
    for (int q = lane; q < 279; q += 64) {
      int ci = q / 9, r = q - ci*9;
      int ky = r / 3, kx = r - ky*3;
      int ih = 2*oh - 1 + ky, iw = 2*ow - 1 + kx;
      float v = 0.f;
      if (ih >= 0 && ih < 128 && iw >= 0 && iw < 128)
        v = x[((b*CIN + ci)*128 + ih)*128 + iw];
      patch[wv][nn][q] = v;
    }
  }
  __syncthreads();
  int c = lane;
  float acc[8];
  float bv = bias[c];
  #pragma unroll
  for (int nn = 0; nn < 8; ++nn) acc[nn] = bv;
  for (int q = 0; q < 279; ++q) {
    float wgt = whT[q*64 + c];
    #pragma unroll
    for (int nn = 0; nn < 8; ++nn) acc[nn] += patch[wv][nn][q] * wgt;
  }
  for (int nn = 0; nn < 8; ++nn) {
    int g = gbase + nn;
    float y = acc[nn];
    yn[g*64 + c] = y;
    unsigned short hb = f2bf(y);
    ynh[g*64 + c] = hb;
    ynl[g*64 + c] = f2bf(y - bf2f(hb));
    float s = y*y;
    #pragma unroll
    for (int off = 32; off > 0; off >>= 1) s += __shfl_xor(s, off);
    if (lane == 0) sq[g] = s;
  }
}

// ---------------- K2: MFMA split-bf16 Gram (transposed S) + fused top-7 -----
// grid (64 i-blocks of 64 rows, 8 j-splits of 512, 2 batches), 256 threads.
// S is stored [i_local][j] (row-major in i) so scan reads are float4.
__global__ __launch_bounds__(256, 4) void k_knn3(const unsigned short* __restrict__ ynh,
                                                 const unsigned short* __restrict__ ynl,
                                                 const float* __restrict__ sq,
                                                 float* __restrict__ pd,
                                                 int* __restrict__ pidx) {
  __shared__ __align__(16) unsigned short Bh[64*72];   // 9216 B
  __shared__ __align__(16) unsigned short Bl[64*72];
  __shared__ __align__(16) float S[64*68];             // 17408 B
  __shared__ __align__(16) float sqj[64];

  int b = blockIdx.z, ib = blockIdx.x, jsp = blockIdx.y;
  int i0 = ib*64;
  int jbase = jsp*512;
  int tid = threadIdx.x;
  int lane = tid & 63, w = tid >> 6;
  int quad = lane >> 4, m = lane & 15;

  const unsigned short* ynh_b = ynh + (size_t)b*NN*64;
  const unsigned short* ynl_b = ynl + (size_t)b*NN*64;

  // wave's i-fragments (used as MFMA B-operand; cols of S^T = i)
  int irow = i0 + w*16 + m;
  bf16x8 bhf[2], blf[2];
  bhf[0] = *(const bf16x8*)(ynh_b + irow*64 + quad*8);
  bhf[1] = *(const bf16x8*)(ynh_b + irow*64 + 32 + quad*8);
  blf[0] = *(const bf16x8*)(ynl_b + irow*64 + quad*8);
  blf[1] = *(const bf16x8*)(ynl_b + irow*64 + 32 + quad*8);
  float sqi = sq[b*NN + irow];

  float d7[7]; int x7[7];
  #pragma unroll
  for (int k = 0; k < 7; ++k) { d7[k] = 3.0e38f; x7[k] = 0x7fffffff; }
  int srow = tid & 63, seg = tid >> 6;   // scan: 4 threads per row, 16 j each

  auto stageB = [&](int c) {
    int jt = jbase + c*64;
    #pragma unroll
    for (int r2 = 0; r2 < 2; ++r2) {
      int row = (tid >> 3) + 32*r2, oct = tid & 7;
      *(uint4*)&Bh[row*72 + oct*8] = *(const uint4*)(ynh_b + (jt + row)*64 + oct*8);
      *(uint4*)&Bl[row*72 + oct*8] = *(const uint4*)(ynl_b + (jt + row)*64 + oct*8);
    }
    if (tid < 64) sqj[tid] = sq[b*NN + jt + tid];
  };

  stageB(0);

  for (int c = 0; c < 8; ++c) {
    __syncthreads();                       // B(c)/sqj(c) ready; S(c-1) scans done
    f32x4 acc[4];
    #pragma unroll 2
    for (int jn = 0; jn < 4; ++jn) {
      const int ro = (jn*16 + m)*72 + quad*8;
      bf16x8 ajh0 = *(const bf16x8*)&Bh[ro];
      bf16x8 ajh1 = *(const bf16x8*)&Bh[ro + 32];
      bf16x8 ajl0 = *(const bf16x8*)&Bl[ro];
      bf16x8 ajl1 = *(const bf16x8*)&Bl[ro + 32];
      f32x4 a = (f32x4){0.f, 0.f, 0.f, 0.f};
      a = __builtin_amdgcn_mfma_f32_16x16x32_bf16(ajh0, bhf[0], a, 0, 0, 0);
      a = __builtin_amdgcn_mfma_f32_16x16x32_bf16(ajh0, blf[0], a, 0, 0, 0);
      a = __builtin_amdgcn_mfma_f32_16x16x32_bf16(ajl0, bhf[0], a, 0, 0, 0);
      a = __builtin_amdgcn_mfma_f32_16x16x32_bf16(ajh1, bhf[1], a, 0, 0, 0);
      a = __builtin_amdgcn_mfma_f32_16x16x32_bf16(ajh1, blf[1], a, 0, 0, 0);
      a = __builtin_amdgcn_mfma_f32_16x16x32_bf16(ajl1, bhf[1], a, 0, 0, 0);
      acc[jn] = a;
    }

    // epilogue: d2 = sqi + sqj - 2*dot; rows of S are i (col = consecutive j)
    #pragma unroll
    for (int jn = 0; jn < 4; ++jn) {
      f32x4 sq4 = *(const f32x4*)&sqj[jn*16 + quad*4];
      f32x4 dv;
      #pragma unroll
      for (int r = 0; r < 4; ++r) dv[r] = sqi + sq4[r] - 2.f*acc[jn][r];
      *(f32x4*)&S[(w*16 + m)*68 + jn*16 + quad*4] = dv;
    }
    __syncthreads();                       // S(c) complete; B(c) free

    // scan: vectorized float4 reads
    int jg0 = jbase + c*64 + seg*16;
    const float* srp = S + srow*68 + seg*16;
    #pragma unroll
    for (int q4 = 0; q4 < 4; ++q4) {
      f32x4 v = *(const f32x4*)(srp + q4*4);
      #pragma unroll
      for (int r = 0; r < 4; ++r) {
        float d = v[r];
        if (d < d7[6]) {                   // strict < : ascending j stable
          int jj = jg0 + q4*4 + r;
          int k = 6;
          #pragma unroll
          for (int t = 5; t >= 0; --t)
            if (d < d7[t]) { d7[t+1] = d7[t]; x7[t+1] = x7[t]; k = t; }
          d7[k] = d; x7[k] = jj;
        }
      }
    }
    if (c < 7) stageB(c + 1);
  }

  // level-1 merge: 4 threads/row -> 7 per (row, split); tie-break by index
  __syncthreads();
  float* cd = S;                 // [64][28] = 7168 B
  int*   ci = (int*)Bh;          // [64][28] = 7168 B <= 9216
  #pragma unroll
  for (int k = 0; k < 7; ++k) {
    cd[srow*28 + seg*7 + k] = d7[k];
    ci[srow*28 + seg*7 + k] = x7[k];
  }
  __syncthreads();
  if (tid < 64) {
    float md[7]; int mi[7];
    #pragma unroll
    for (int k = 0; k < 7; ++k) { md[k] = 3.0e38f; mi[k] = 0x7fffffff; }
    for (int e = 0; e < 28; ++e) {
      float d = cd[tid*28 + e]; int jj = ci[tid*28 + e];
      if (d < md[6] || (d == md[6] && jj < mi[6])) {
        int k = 6;
        #pragma unroll
        for (int t = 5; t >= 0; --t)
          if (d < md[t] || (d == md[t] && jj < mi[t])) { md[t+1] = md[t]; mi[t+1] = mi[t]; k = t; }
        md[k] = d; mi[k] = jj;
      }
    }
    int g = b*NN + i0 + tid;
    int base = (g*NCH + jsp)*7;
    #pragma unroll
    for (int k = 0; k < 7; ++k) { pd[base+k] = md[k]; pidx[base+k] = mi[k]; }
  }
}

// ---------------- K3: merge per-split top7 -> final 7 neighbors --------------
__global__ __launch_bounds__(256) void k_merge(const float* __restrict__ pd,
                                               const int* __restrict__ pidx,
                                               int* __restrict__ nbr) {
  int g = blockIdx.x*256 + threadIdx.x;
  float d7[7]; int x7[7];
  #pragma unroll
  for (int k = 0; k < 7; ++k) { d7[k] = 3.0e38f; x7[k] = 0x7fffffff; }
  int base = g*NCH*7;
  for (int e = 0; e < NCH*7; ++e) {
    float d = pd[base+e]; int jj = pidx[base+e];
    if (d < d7[6]) {
      int k = 6;
      #pragma unroll
      for (int t = 5; t >= 0; --t) {
        if (d < d7[t]) { d7[t+1] = d7[t]; x7[t+1] = x7[t]; k = t; }
      }
      d7[k] = d; x7[k] = jj;
    }
  }
  #pragma unroll
  for (int k = 0; k < 7; ++k) nbr[g*7 + k] = x7[k];
}

// ---------------- K4: hcat = yn @ [W0|W1] + fused f-vectors -----------------
__global__ __launch_bounds__(256) void k_hcat(const float* __restrict__ yn,
                                              const float* __restrict__ W0,
                                              const float* __restrict__ W1,
                                              const float* __restrict__ a0,
                                              const float* __restrict__ a1,
                                              float* __restrict__ hcat,
                                              float* __restrict__ fv) {
  __shared__ float Ws[64*128];
  __shared__ float yt[16*64];
  int b = blockIdx.x >> 8, n0 = (blockIdx.x & 255)*16;
  int tid = threadIdx.x;
  for (int idx = tid; idx < 8192; idx += 256) {
    int k = idx >> 7, c = idx & 127;
    Ws[idx] = (c < 64) ? W0[k*64 + c] : W1[k*64 + (c - 64)];
  }
  {
    const float4* src = (const float4*)(yn + (b*NN + n0)*64);
    for (int idx = tid; idx < 256; idx += 256) ((float4*)yt)[idx] = src[idx];
  }
  __syncthreads();
  int c = tid & 127, nh = tid >> 7;
  int lane = tid & 63;
  int head = (c >= 64);
  float av1 = head ? a1[lane] : a0[lane];
  float av2 = head ? a1[64 + lane] : a0[64 + lane];
  for (int nn = 0; nn < 8; ++nn) {
    int node = nh*8 + nn;
    const float* yr = yt + node*64;
    float acc = 0.f;
    #pragma unroll
    for (int k = 0; k < 64; ++k) acc += yr[k] * Ws[k*128 + c];
    hcat[(b*NN + n0 + node)*128 + c] = acc;
    // fused attention dots (wave = 64 cols of one head)
    float s1 = acc*av1, s2 = acc*av2;
    #pragma unroll
    for (int off = 32; off > 0; off >>= 1) {
      s1 += __shfl_xor(s1, off); s2 += __shfl_xor(s2, off);
    }
    if (lane == 0) {
      int gg = (b << 12) + n0 + node;
      fv[head*16384 + gg] = s1;
      fv[head*16384 + 8192 + gg] = s2;
    }
  }
}

// ---------------- K6: GAT layer1 aggregation (2 heads) + relu ---------------
__global__ __launch_bounds__(256) void k_agg1(const float* __restrict__ hcat,
                                              const float* __restrict__ fv,
                                              const int* __restrict__ nbr,
                                              float* __restrict__ hagg) {
  int g = blockIdx.x*2 + (threadIdx.x >> 7);
  int c = threadIdx.x & 127;
  int b = g >> 12;
  int head = c >> 6;
  int jj[7];
  #pragma unroll
  for (int t = 0; t < 7; ++t) jj[t] = nbr[g*7 + t];
  float f1 = fv[head*16384 + g];
  const float* f2p = fv + head*16384 + 8192 + (b << 12);
  float e[7], mx = -3.0e38f;
  #pragma unroll
  for (int t = 0; t < 7; ++t) {
    float v = f1 + f2p[jj[t]];
    v = (v >= 0.f) ? v : 0.2f*v;
    e[t] = v; mx = fmaxf(mx, v);
  }
  float wgt[7], s = 0.f;
  #pragma unroll
  for (int t = 0; t < 7; ++t) { wgt[t] = expf(e[t] - mx); s += wgt[t]; }
  float acc = 0.f;
  #pragma unroll
  for (int t = 0; t < 7; ++t)
    acc += (wgt[t]/s) * hcat[((b << 12) + jj[t])*128 + c];
  hagg[g*128 + c] = fmaxf(acc, 0.f);
}

// ---------------- K7: ho = hagg @ W_out + fused f-vectors -------------------
__global__ __launch_bounds__(256) void k_ho(const float* __restrict__ hagg,
                                            const float* __restrict__ Wout,
                                            const float* __restrict__ aout,
                                            float* __restrict__ ho,
                                            float* __restrict__ fo) {
  __shared__ float Ws[128*64];
  __shared__ float ht[16*128];
  int b = blockIdx.x >> 8, n0 = (blockIdx.x & 255)*16;
  int tid = threadIdx.x;
  for (int idx = tid; idx < 8192; idx += 256) Ws[idx] = Wout[idx];
  {
    const float4* src = (const float4*)(hagg + (b*NN + n0)*128);
    for (int idx = tid; idx < 512; idx += 256) ((float4*)ht)[idx] = src[idx];
  }
  __syncthreads();
  int c = tid & 63, ngrp = tid >> 6;
  float av1 = aout[c], av2 = aout[64 + c];
  for (int nn = 0; nn < 4; ++nn) {
    int node = ngrp*4 + nn;
    const float* hr = ht + node*128;
    float acc = 0.f;
    #pragma unroll
    for (int k = 0; k < 128; ++k) acc += hr[k] * Ws[k*64 + c];
    ho[(b*NN + n0 + node)*64 + c] = acc;
    float s1 = acc*av1, s2 = acc*av2;
    #pragma unroll
    for (int off = 32; off > 0; off >>= 1) {
      s1 += __shfl_xor(s1, off); s2 += __shfl_xor(s2, off);
    }
    if (c == 0) {
      int gg = (b << 12) + n0 + node;
      fo[gg] = s1;
      fo[8192 + gg] = s2;
    }
  }
}

// ---------------- K9: layer2 agg + elu + log_softmax ------------------------
__global__ __launch_bounds__(256) void k_agg2(const float* __restrict__ ho,
                                              const float* __restrict__ fo,
                                              const int* __restrict__ nbr,
                                              float* __restrict__ zbuf) {
  int g = blockIdx.x*4 + (threadIdx.x >> 6);
  int c = threadIdx.x & 63;
  int b = g >> 12;
  int jj[7];
  #pragma unroll
  for (int t = 0; t < 7; ++t) jj[t] = nbr[g*7 + t];
  float f1 = fo[g];
  const float* f2p = fo + 8192 + (b << 12);
  float e[7], mx = -3.0e38f;
  #pragma unroll
  for (int t = 0; t < 7; ++t) {
    float v = f1 + f2p[jj[t]];
    v = (v >= 0.f) ? v : 0.2f*v;
    e[t] = v; mx = fmaxf(mx, v);
  }
  float wgt[7], s = 0.f;
  #pragma unroll
  for (int t = 0; t < 7; ++t) { wgt[t] = expf(e[t] - mx); s += wgt[t]; }
  float acc = 0.f;
  #pragma unroll
  for (int t = 0; t < 7; ++t)
    acc += (wgt[t]/s) * ho[((b << 12) + jj[t])*64 + c];
  float v = (acc > 0.f) ? acc : expm1f(acc);
  float mm = v;
  #pragma unroll
  for (int off = 32; off > 0; off >>= 1) mm = fmaxf(mm, __shfl_xor(mm, off));
  float ex = expf(v - mm), ss = ex;
  #pragma unroll
  for (int off = 32; off > 0; off >>= 1) ss += __shfl_xor(ss, off);
  zbuf[g*64 + c] = v - mm - logf(ss);
}

// ---------------- K10: ConvTranspose2d v2 — per-row tap-looped LDS matmul ---
__global__ __launch_bounds__(256) void k_convt2(const float* __restrict__ z,
                                                const float* __restrict__ wT,
                                                const float* __restrict__ bias,
                                                float* __restrict__ out) {
  __shared__ __align__(16) float lds[12800];   // 51200 B
  float* zt = lds;              // [2 rows][64 ci][68]
  float* ws = lds + 8704;       // [64 ci][64 co]
  float* so = lds;              // [64 co][129] epilogue alias

  int oy = blockIdx.x, b = blockIdx.y;
  int r = oy >> 1, pi = oy & 1;
  int tid = threadIdx.x;
  int colo = tid & 15, pgrp = tid >> 4;
  int co4 = colo*4, m0 = pgrp*4;

  int nrows = pi ? 2 : 1;
  for (int row = 0; row < nrows; ++row) {
    int iy = r + row;
    const float* zsrc = z + (((b << 12) + iy*64) << 6);
    for (int idx = tid; idx < 4352; idx += 256) {
      int ix = idx >> 6, ci = idx & 63;
      float v = 0.f;
      if (ix < 64 && iy < 64) v = zsrc[ix*64 + ci];
      zt[row*4352 + ci*68 + ix] = v;
    }
  }

  float acc[2][4][4];
  {
    float4 bv = *(const float4*)&bias[co4];
    #pragma unroll
    for (int chi = 0; chi < 2; ++chi)
      #pragma unroll
      for (int k = 0; k < 4; ++k) {
        acc[chi][k][0] = bv.x; acc[chi][k][1] = bv.y;
        acc[chi][k][2] = bv.z; acc[chi][k][3] = bv.w;
      }
  }

  int kys[2], rows[2], nky;
  if (pi == 0) { kys[0] = 1; rows[0] = 0; nky = 1; }
  else         { kys[0] = 2; rows[0] = 0; kys[1] = 0; rows[1] = 1; nky = 2; }

  for (int t = 0; t < nky; ++t) {
    const float* zrow = zt + rows[t]*4352;
    for (int kx = 0; kx < 3; ++kx) {
      const float* wsrc = wT + (kys[t]*3 + kx)*4096;
      __syncthreads();
      for (int idx = tid; idx < 4096; idx += 256) ws[idx] = wsrc[idx];
      __syncthreads();
      int chi = (kx == 1) ? 0 : 1;
      int xoff = (kx == 0) ? 1 : 0;
      float* ap = &acc[chi][0][0];
      for (int ci = 0; ci < 64; ++ci) {
        float4 wv = *(const float4*)&ws[ci*64 + co4];
        const float* zp = zrow + ci*68 + m0;
        float4 zv;
        if (xoff == 0) {
          zv = *(const float4*)zp;
        } else {
          float4 a0 = *(const float4*)zp;
          float4 a1 = *(const float4*)(zp + 4);
          zv.x = a0.y; zv.y = a0.z; zv.z = a0.w; zv.w = a1.x;
        }
        #pragma unroll
        for (int k = 0; k < 4; ++k) {
          float zk = (&zv.x)[k];
          ap[k*4+0] += zk * wv.x;
          ap[k*4+1] += zk * wv.y;
          ap[k*4+2] += zk * wv.z;
          ap[k*4+3] += zk * wv.w;
        }
      }
    }
  }

  __syncthreads();
  #pragma unroll
  for (int chi = 0; chi < 2; ++chi)
    #pragma unroll
    for (int k = 0; k < 4; ++k)
      #pragma unroll
      for (int cc = 0; cc < 4; ++cc)
        so[(co4 + cc)*129 + 2*(m0 + k) + chi] = acc[chi][k][cc];
  __syncthreads();
  for (int idx = tid; idx < 8192; idx += 256) {
    int co = idx >> 7, ox = idx & 127;
    out[(((b << 6) + co)*128 + oy)*128 + ox] = so[co*129 + ox];
  }
}

// ---------------- launch ----------------------------------------------------
extern "C" void kernel_launch(void* const* d_in, const int* in_sizes, int n_in,
                              void* d_out, int out_size, void* d_ws, size_t ws_size,
                              hipStream_t stream) {
  const float* x      = (const float*)d_in[0];
  const float* w_head = (const float*)d_in[1];
  const float* b_head = (const float*)d_in[2];
  const float* W0     = (const float*)d_in[3];
  const float* a0     = (const float*)d_in[4];
  const float* W1     = (const float*)d_in[5];
  const float* a1     = (const float*)d_in[6];
  const float* W_out  = (const float*)d_in[7];
  const float* a_out  = (const float*)d_in[8];
  const float* w_last = (const float*)d_in[9];
  const float* b_last = (const float*)d_in[10];
  float* out = (float*)d_out;

  float* wsf = (float*)d_ws;
  int*   wsi = (int*)d_ws;
  float* yn   = wsf + OF_YN;
  float* sq   = wsf + OF_SQ;
  float* hcat = wsf + OF_HCAT;
  float* fv   = wsf + OF_FV;
  float* hagg = wsf + OF_HAGG;
  float* ho   = wsf + OF_HO;
  float* fo   = wsf + OF_FO;
  float* zbuf = wsf + OF_Z;
  float* pd   = wsf + OF_PD;
  int*   pidx = wsi + OF_PI;
  int*   nbr  = wsi + OF_NBR;
  float* wT   = wsf + OF_WT;
  float* whT  = wsf + OF_WHT;
  unsigned short* ynh = (unsigned short*)(wsf + OF_YNH);
  unsigned short* ynl = (unsigned short*)(wsf + OF_YNL);

  hipLaunchKernelGGL(k_prep,  dim3(214), dim3(256), 0, stream, w_last, w_head, wT, whT);
  hipLaunchKernelGGL(k_head,  dim3(256), dim3(256), 0, stream, x, whT, b_head, yn, sq, ynh, ynl);
  hipLaunchKernelGGL(k_knn3,  dim3(64, NCH, 2), dim3(256), 0, stream, ynh, ynl, sq, pd, pidx);
  hipLaunchKernelGGL(k_merge, dim3(32), dim3(256), 0, stream, pd, pidx, nbr);
  hipLaunchKernelGGL(k_hcat,  dim3(512), dim3(256), 0, stream, yn, W0, W1, a0, a1, hcat, fv);
  hipLaunchKernelGGL(k_agg1,  dim3(4096), dim3(256), 0, stream, hcat, fv, nbr, hagg);
  hipLaunchKernelGGL(k_ho,    dim3(512), dim3(256), 0, stream, hagg, W_out, a_out, ho, fo);
  hipLaunchKernelGGL(k_agg2,  dim3(2048), dim3(256), 0, stream, ho, fo, nbr, zbuf);
  hipLaunchKernelGGL(k_convt2, dim3(128, 2), dim3(256), 0, stream, zbuf, wT, b_last, out);
}